// Round 1
// baseline (762.013 us; speedup 1.0000x reference)
//
#include <hip/hip_runtime.h>
#include <hip/hip_bf16.h>

#define B_   2
#define C_   128
#define D_   6
#define H_   56
#define W_   56
#define N_   12      // B_*D_
#define G_   4
#define CG   32
#define COUT 128
#define K2_  9
#define OFFC 72      // 2*G*K2
#define HW   3136
#define CSTR (D_*HW) // x stride per channel = 18816

// deform LDS layout strides (floats), chosen for bank-conflict-free b128 reads:
// shift(lane) = (p0*PS + g*GS) % 32 = 8*ph + 4*g  -> {0,4,8,...,28}, disjoint quads
#define PS 1300
#define GS 324
#define KS 36

// ---------------- transpose x (b,c,d,h,w) -> xcl (n,h,w,c), n=b*D+d ----------------
__global__ void k_transpose(const float* __restrict__ x, float* __restrict__ xcl) {
  __shared__ float tile[32][57];
  const int h = blockIdx.x, c0 = blockIdx.y * 32, n = blockIdx.z;
  const int b = n / D_, d = n % D_;
  const float* src = x + (((size_t)(b * C_ + c0) * D_ + d) * HW) + h * W_;
  for (int i = threadIdx.x; i < 32 * W_; i += 256) {
    const int c = i / W_, w = i - c * W_;
    tile[c][w] = src[(size_t)c * CSTR + w];
  }
  __syncthreads();
  float* dst = xcl + ((size_t)(n * H_ + h) * W_) * C_ + c0;
  for (int i = threadIdx.x; i < 32 * W_; i += 256) {
    const int w = i >> 5, c = i & 31;
    dst[(size_t)w * C_ + c] = tile[c][w];
  }
}

// ---------------- conv_w (co, c, ky, kx) -> wtt (co, k, c) ----------------
__global__ void k_wt_transpose(const float* __restrict__ cw, float* __restrict__ wtt) {
  const int idx = blockIdx.x * 256 + threadIdx.x;
  if (idx < COUT * CG * K2_) {
    const int co = idx / 288;
    const int rem = idx - co * 288;
    const int k = rem >> 5;
    const int c = rem & 31;
    wtt[idx] = cw[((size_t)co * CG + c) * K2_ + k];
  }
}

// ---------------- offset conv: 3x3, Cin=128, Cout=72, pad 1 ----------------
// grid (14, 9, N_), block 256 = 4 rows x 64 lanes; 8 output channels per thread
__global__ __launch_bounds__(256) void k_offset_conv(const float* __restrict__ x,
    const float* __restrict__ ow, const float* __restrict__ ob,
    float* __restrict__ off) {
  const int n = blockIdx.z;
  const int co0 = blockIdx.y * 8;
  const int r = threadIdx.x >> 6;
  const int w = threadIdx.x & 63;
  const int h = blockIdx.x * 4 + r;
  const int b = n / D_, d = n % D_;
  const float* xb = x + ((size_t)b * C_ * D_ + d) * HW;
  float acc[8];
#pragma unroll
  for (int j = 0; j < 8; ++j) acc[j] = ob[co0 + j];
  for (int c = 0; c < C_; ++c) {
    const float* xc = xb + (size_t)c * CSTR;
    const float* wt = ow + ((size_t)co0 * C_ + c) * 9;
#pragma unroll
    for (int ky = 0; ky < 3; ++ky) {
      const int y = h + ky - 1;
      if ((unsigned)y < (unsigned)H_) {
        const float* xr = xc + y * W_;
#pragma unroll
        for (int kx = 0; kx < 3; ++kx) {
          const int xx = w + kx - 1;
          const float v = ((unsigned)xx < (unsigned)W_) ? xr[xx] : 0.f;
          const int wi = ky * 3 + kx;
#pragma unroll
          for (int j = 0; j < 8; ++j)
            acc[j] = fmaf(v, wt[(size_t)j * (C_ * 9) + wi], acc[j]);
        }
      }
    }
  }
  if (w < W_) {
#pragma unroll
    for (int j = 0; j < 8; ++j)
      off[((size_t)n * OFFC + co0 + j) * HW + h * W_ + w] = acc[j];
  }
}

// ---------------- deformable conv ----------------
// grid (7, H_, N_), block 128. 8-pixel strip per block.
__global__ __launch_bounds__(128) void k_deform(const float* __restrict__ xcl,
    const float* __restrict__ offb, const float* __restrict__ wtt,
    const float* __restrict__ cb, float* __restrict__ out) {
  __shared__ __align__(16) float s[8 * PS];
  __shared__ __align__(16) float outs[COUT][12];
  const int w0 = blockIdx.x * 8;
  const int h = blockIdx.y;
  const int n = blockIdx.z;
  const int t = threadIdx.x;
  const int b = n / D_, d = n % D_;

  // Phase A: bilinear sampling -> s[p][g][k][c]
  {
    const int c = t & 31;
    const int g = t >> 5;
    const float* xg = xcl + (size_t)n * HW * C_ + g * CG + c;
    const size_t offbase = ((size_t)n * OFFC + g * (K2_ * 2)) * HW + h * W_ + w0;
    for (int k = 0; k < K2_; ++k) {
      const int ky = k / 3 - 1;
      const int kx = k - (k / 3) * 3 - 1;
      const float* offY = offb + offbase + (size_t)(2 * k) * HW;
      const float* offX = offY + HW;
      const float4 oyA = *(const float4*)offY;
      const float4 oyB = *(const float4*)(offY + 4);
      const float4 oxA = *(const float4*)offX;
      const float4 oxB = *(const float4*)(offX + 4);
      const float oy[8] = {oyA.x, oyA.y, oyA.z, oyA.w, oyB.x, oyB.y, oyB.z, oyB.w};
      const float ox[8] = {oxA.x, oxA.y, oxA.z, oxA.w, oxB.x, oxB.y, oxB.z, oxB.w};
#pragma unroll
      for (int p = 0; p < 8; ++p) {
        const float py = (float)(h + ky) + oy[p];
        const float px = (float)(w0 + p + kx) + ox[p];
        const float y0f = floorf(py), x0f = floorf(px);
        const float ly = py - y0f, lx = px - x0f;
        const int y0 = (int)y0f, x0 = (int)x0f;
        const int y1 = y0 + 1, x1 = x0 + 1;
        const int yc0 = min(max(y0, 0), H_ - 1), yc1 = min(max(y1, 0), H_ - 1);
        const int xc0 = min(max(x0, 0), W_ - 1), xc1 = min(max(x1, 0), W_ - 1);
        const float my0 = ((unsigned)y0 < (unsigned)H_) ? 1.f : 0.f;
        const float my1 = ((unsigned)y1 < (unsigned)H_) ? 1.f : 0.f;
        const float mx0 = ((unsigned)x0 < (unsigned)W_) ? 1.f : 0.f;
        const float mx1 = ((unsigned)x1 < (unsigned)W_) ? 1.f : 0.f;
        const float v00 = xg[(size_t)(yc0 * W_ + xc0) * C_];
        const float v01 = xg[(size_t)(yc0 * W_ + xc1) * C_];
        const float v10 = xg[(size_t)(yc1 * W_ + xc0) * C_];
        const float v11 = xg[(size_t)(yc1 * W_ + xc1) * C_];
        const float w00 = (1.f - ly) * (1.f - lx) * my0 * mx0;
        const float w01 = (1.f - ly) * lx * my0 * mx1;
        const float w10 = ly * (1.f - lx) * my1 * mx0;
        const float w11 = ly * lx * my1 * mx1;
        s[p * PS + g * GS + k * KS + c] =
            fmaf(w00, v00, fmaf(w01, v01, fmaf(w10, v10, w11 * v11)));
      }
    }
  }
  __syncthreads();

  // Phase B: per-pixel grouped mat-vec. thread -> (g, o0, ph): 4 co x 2 pixels
  {
    const int g = t >> 5;
    const int rr = t & 31;
    const int o0 = rr & 7;
    const int ph = rr >> 3;
    const int p0 = ph * 2;
    int co[4];
    float acc[4][2];
#pragma unroll
    for (int j = 0; j < 4; ++j) {
      co[j] = g * CG + o0 + j * 8;
      acc[j][0] = acc[j][1] = cb[co[j]];
    }
    for (int k = 0; k < K2_; ++k) {
      const float* sp0 = &s[p0 * PS + g * GS + k * KS];
      const float* sp1 = sp0 + PS;
#pragma unroll
      for (int ci = 0; ci < 8; ++ci) {
        const float4 s0 = *(const float4*)&sp0[ci * 4];
        const float4 s1 = *(const float4*)&sp1[ci * 4];
#pragma unroll
        for (int j = 0; j < 4; ++j) {
          const float4 wv = *(const float4*)&wtt[((size_t)co[j] * K2_ + k) * 32 + ci * 4];
          acc[j][0] = fmaf(wv.x, s0.x, fmaf(wv.y, s0.y, fmaf(wv.z, s0.z, fmaf(wv.w, s0.w, acc[j][0]))));
          acc[j][1] = fmaf(wv.x, s1.x, fmaf(wv.y, s1.y, fmaf(wv.z, s1.z, fmaf(wv.w, s1.w, acc[j][1]))));
        }
      }
    }
#pragma unroll
    for (int j = 0; j < 4; ++j) {
      outs[co[j]][p0] = acc[j][0];
      outs[co[j]][p0 + 1] = acc[j][1];
    }
  }
  __syncthreads();

  // coalesced-ish output: thread t = channel, 2x float4 (32B) per row
  {
    const int co = t;
    const float4 a = *(const float4*)&outs[co][0];
    const float4 bq = *(const float4*)&outs[co][4];
    float* dst = out + (((size_t)(b * COUT + co) * D_ + d) * HW) + h * W_ + w0;
    *(float4*)&dst[0] = a;
    *(float4*)&dst[4] = bq;
  }
}

// ---------------- instance norm over (D,H,W) + exact GELU, in-place ----------------
__global__ __launch_bounds__(256) void k_norm_gelu(float* __restrict__ io) {
  const int M = D_ * HW; // 18816
  float* p = io + (size_t)blockIdx.x * M;
  float s = 0.f, s2 = 0.f;
  for (int i = threadIdx.x; i < M; i += 256) {
    const float v = p[i];
    s += v;
    s2 = fmaf(v, v, s2);
  }
#pragma unroll
  for (int off = 32; off > 0; off >>= 1) {
    s += __shfl_down(s, off, 64);
    s2 += __shfl_down(s2, off, 64);
  }
  __shared__ float rs[4], rs2[4];
  __shared__ float smu, srstd;
  const int wid = threadIdx.x >> 6, lane = threadIdx.x & 63;
  if (lane == 0) { rs[wid] = s; rs2[wid] = s2; }
  __syncthreads();
  if (threadIdx.x == 0) {
    const float ts = rs[0] + rs[1] + rs[2] + rs[3];
    const float t2 = rs2[0] + rs2[1] + rs2[2] + rs2[3];
    const float mu = ts / (float)M;
    const float var = t2 / (float)M - mu * mu;
    smu = mu;
    srstd = rsqrtf(var + 1e-5f);
  }
  __syncthreads();
  const float mu = smu, rstd = srstd;
  for (int i = threadIdx.x; i < M; i += 256) {
    const float v = (p[i] - mu) * rstd;
    p[i] = 0.5f * v * (1.f + erff(v * 0.70710678118654752f));
  }
}

extern "C" void kernel_launch(void* const* d_in, const int* in_sizes, int n_in,
                              void* d_out, int out_size, void* d_ws, size_t ws_size,
                              hipStream_t stream) {
  const float* x  = (const float*)d_in[0];
  const float* ow = (const float*)d_in[1];
  const float* ob = (const float*)d_in[2];
  const float* cw = (const float*)d_in[3];
  const float* cb = (const float*)d_in[4];
  float* outp = (float*)d_out;

  float* xcl  = (float*)d_ws;                       // 4,816,896 floats
  float* offb = xcl + (size_t)N_ * HW * C_;         // 2,709,504 floats
  float* wtt  = offb + (size_t)N_ * OFFC * HW;      // 36,864 floats  (total ~30.3 MB)

  k_transpose<<<dim3(H_, 4, N_), 256, 0, stream>>>(x, xcl);
  k_wt_transpose<<<dim3(144), 256, 0, stream>>>(cw, wtt);
  k_offset_conv<<<dim3(14, 9, N_), 256, 0, stream>>>(x, ow, ob, offb);
  k_deform<<<dim3(7, H_, N_), 128, 0, stream>>>(xcl, offb, wtt, cb, outp);
  k_norm_gelu<<<dim3(B_ * COUT), 256, 0, stream>>>(outp);
}

// Round 2
// 427.456 us; speedup vs baseline: 1.7827x; 1.7827x over previous
//
#include <hip/hip_runtime.h>
#include <hip/hip_bf16.h>

#define B_   2
#define C_   128
#define D_   6
#define H_   56
#define W_   56
#define N_   12      // B_*D_
#define G_   4
#define CG   32
#define COUT 128
#define K2_  9
#define OFFC 72      // 2*G*K2
#define HW   3136
#define CSTR (D_*HW) // x stride per channel = 18816

// deform LDS strides (floats):
// KS=32 (no pad), GS=296 (=9*32+8 pad -> each g lands in distinct bank octet),
// PS=4*GS=1184 (PS%32==0 -> phase-A writes are 2-way bank aliases = free)
#define KS 32
#define GS 296
#define PS 1184

// ---------------- transpose x (b,c,d,h,w) -> xcl (n,h,w,c), n=b*D+d ----------------
__global__ void k_transpose(const float* __restrict__ x, float* __restrict__ xcl) {
  __shared__ float tile[32][57];
  const int h = blockIdx.x, c0 = blockIdx.y * 32, n = blockIdx.z;
  const int b = n / D_, d = n % D_;
  const float* src = x + (((size_t)(b * C_ + c0) * D_ + d) * HW) + h * W_;
  for (int i = threadIdx.x; i < 32 * W_; i += 256) {
    const int c = i / W_, w = i - c * W_;
    tile[c][w] = src[(size_t)c * CSTR + w];
  }
  __syncthreads();
  float* dst = xcl + ((size_t)(n * H_ + h) * W_) * C_ + c0;
  for (int i = threadIdx.x; i < 32 * W_; i += 256) {
    const int w = i >> 5, c = i & 31;
    dst[(size_t)w * C_ + c] = tile[c][w];
  }
}

// ---------------- conv_w (co, c, ky, kx) -> wtt2[k][ci][co][e] ----------------
// wtt2[((k*8+ci)*128 + co)*4 + e] = cw[(co*32 + ci*4 + e)*9 + k]
__global__ void k_wt2(const float* __restrict__ cw, float* __restrict__ wtt2) {
  const int idx = blockIdx.x * 256 + threadIdx.x; // < 36864
  if (idx < COUT * CG * K2_) {
    const int e = idx & 3;
    const int co = (idx >> 2) & 127;
    const int kci = idx >> 9;
    const int ci = kci & 7;
    const int k = kci >> 3;
    wtt2[idx] = cw[((size_t)co * CG + ci * 4 + e) * K2_ + k];
  }
}

// ---------------- offset_w (co, c, ky, kx) -> owt[(c*9+wi)*OFFC + co] ----------------
__global__ void k_owt(const float* __restrict__ ow, float* __restrict__ owt) {
  const int idx = blockIdx.x * 256 + threadIdx.x; // < 82944
  if (idx < OFFC * C_ * K2_) {
    const int co = idx % OFFC;
    const int cwi = idx / OFFC;
    const int wi = cwi % 9;
    const int c = cwi / 9;
    owt[idx] = ow[((size_t)co * C_ + c) * K2_ + wi];
  }
}

// ---------------- offset conv: 3x3, Cin=128, Cout=72, pad 1 ----------------
// grid (14, 9, N_), block 256 = 4 rows x 64 lanes; 8 output channels per thread
__global__ __launch_bounds__(256) void k_offset_conv(const float* __restrict__ x,
    const float* __restrict__ owt, const float* __restrict__ ob,
    float* __restrict__ off) {
  const int n = blockIdx.z;
  const int co0 = blockIdx.y * 8;
  const int r = threadIdx.x >> 6;
  const int w = threadIdx.x & 63;
  const int h = blockIdx.x * 4 + r;
  const int b = n / D_, d = n % D_;
  const float* xb = x + ((size_t)b * C_ * D_ + d) * HW + h * W_;
  float acc[8];
#pragma unroll
  for (int j = 0; j < 8; ++j) acc[j] = ob[co0 + j];
#pragma unroll 2
  for (int c = 0; c < C_; ++c) {
    const float* xc = xb + (size_t)c * CSTR;
    const float* wc = owt + (size_t)c * (9 * OFFC) + co0;
#pragma unroll
    for (int ky = 0; ky < 3; ++ky) {
      const int y = h + ky - 1;
      if ((unsigned)y < (unsigned)H_) {
        const float* xr = xc + (ky - 1) * W_;
#pragma unroll
        for (int kx = 0; kx < 3; ++kx) {
          const int xx = w + kx - 1;
          const float v = ((unsigned)xx < (unsigned)W_) ? xr[xx] : 0.f;
          const float* wr = wc + (ky * 3 + kx) * OFFC;
#pragma unroll
          for (int j = 0; j < 8; ++j)
            acc[j] = fmaf(v, wr[j], acc[j]);
        }
      }
    }
  }
  if (w < W_) {
#pragma unroll
    for (int j = 0; j < 8; ++j)
      off[((size_t)n * OFFC + co0 + j) * HW + h * W_ + w] = acc[j];
  }
}

// ---------------- deformable conv ----------------
// grid (7, H_, N_), block 256. 8-pixel strip per block. 3 blocks/CU (44KB LDS).
__global__ __launch_bounds__(256) void k_deform(const float* __restrict__ xcl,
    const float* __restrict__ offb, const float* __restrict__ wtt2,
    const float* __restrict__ cb, float* __restrict__ out) {
  __shared__ __align__(16) float s[8 * PS];       // 37,888 B
  __shared__ __align__(16) float outs[COUT][12];  //  6,144 B
  const int w0 = blockIdx.x * 8;
  const int h = blockIdx.y;
  const int n = blockIdx.z;
  const int t = threadIdx.x;
  const int b = n / D_, d = n % D_;

  // Phase A: bilinear sampling -> s[p][g][k][c]; thread = (c, p)
  {
    const int c = t & 31;
    const int p = t >> 5;        // 0..7
    const int w = w0 + p;
    const float* xgn = xcl + (size_t)n * HW * C_ + c;
    float* sp = &s[p * PS + c];
#pragma unroll
    for (int g = 0; g < G_; ++g) {
      const float* ob2 = offb + ((size_t)n * OFFC + g * 18) * HW + h * W_ + w;
      float oy[9], ox[9];
#pragma unroll
      for (int k = 0; k < 9; ++k) {
        oy[k] = ob2[(size_t)(2 * k) * HW];
        ox[k] = ob2[(size_t)(2 * k + 1) * HW];
      }
      const float* xg = xgn + g * CG;
      float* spg = sp + g * GS;
#pragma unroll 3
      for (int k = 0; k < 9; ++k) {
        const int ky = k / 3 - 1;
        const int kx = k - (k / 3) * 3 - 1;
        const float py = (float)(h + ky) + oy[k];
        const float px = (float)(w + kx) + ox[k];
        const float y0f = floorf(py), x0f = floorf(px);
        const float ly = py - y0f, lx = px - x0f;
        const int y0 = (int)y0f, x0 = (int)x0f;
        const int y1 = y0 + 1, x1 = x0 + 1;
        const int yc0 = min(max(y0, 0), H_ - 1), yc1 = min(max(y1, 0), H_ - 1);
        const int xc0 = min(max(x0, 0), W_ - 1), xc1 = min(max(x1, 0), W_ - 1);
        const float my0 = ((unsigned)y0 < (unsigned)H_) ? 1.f : 0.f;
        const float my1 = ((unsigned)y1 < (unsigned)H_) ? 1.f : 0.f;
        const float mx0 = ((unsigned)x0 < (unsigned)W_) ? 1.f : 0.f;
        const float mx1 = ((unsigned)x1 < (unsigned)W_) ? 1.f : 0.f;
        const float v00 = xg[(size_t)(yc0 * W_ + xc0) * C_];
        const float v01 = xg[(size_t)(yc0 * W_ + xc1) * C_];
        const float v10 = xg[(size_t)(yc1 * W_ + xc0) * C_];
        const float v11 = xg[(size_t)(yc1 * W_ + xc1) * C_];
        const float w00 = (1.f - ly) * (1.f - lx) * my0 * mx0;
        const float w01 = (1.f - ly) * lx * my0 * mx1;
        const float w10 = ly * (1.f - lx) * my1 * mx0;
        const float w11 = ly * lx * my1 * mx1;
        spg[k * KS] =
            fmaf(w00, v00, fmaf(w01, v01, fmaf(w10, v10, w11 * v11)));
      }
    }
  }
  __syncthreads();

  // Phase B: per-pixel grouped mat-vec. thread = (co, 4-pixel half)
  {
    const int co = t & 127;
    const int ph = t >> 7;       // 0..1
    const int g = co >> 5;
    const float* sb = &s[(ph * 4) * PS + g * GS];
    const float bias = cb[co];
    float a0 = bias, a1 = bias, a2 = bias, a3 = bias;
    for (int k = 0; k < K2_; ++k) {
#pragma unroll
      for (int ci = 0; ci < 8; ++ci) {
        const float4 wv = *(const float4*)&wtt2[(((size_t)(k * 8 + ci)) * 128 + co) * 4];
        const float4 s0 = *(const float4*)&sb[0 * PS + k * KS + ci * 4];
        const float4 s1 = *(const float4*)&sb[1 * PS + k * KS + ci * 4];
        const float4 s2 = *(const float4*)&sb[2 * PS + k * KS + ci * 4];
        const float4 s3 = *(const float4*)&sb[3 * PS + k * KS + ci * 4];
        a0 = fmaf(wv.x, s0.x, fmaf(wv.y, s0.y, fmaf(wv.z, s0.z, fmaf(wv.w, s0.w, a0))));
        a1 = fmaf(wv.x, s1.x, fmaf(wv.y, s1.y, fmaf(wv.z, s1.z, fmaf(wv.w, s1.w, a1))));
        a2 = fmaf(wv.x, s2.x, fmaf(wv.y, s2.y, fmaf(wv.z, s2.z, fmaf(wv.w, s2.w, a2))));
        a3 = fmaf(wv.x, s3.x, fmaf(wv.y, s3.y, fmaf(wv.z, s3.z, fmaf(wv.w, s3.w, a3))));
      }
    }
    float* op = &outs[co][ph * 4];
    op[0] = a0; op[1] = a1; op[2] = a2; op[3] = a3;
  }
  __syncthreads();

  // output: 2 lanes per channel row, one float4 each (32B/row)
  {
    const int co = t >> 1;
    const int half = t & 1;
    const float4 v = *(const float4*)&outs[co][half * 4];
    float* dst = out + (((size_t)(b * COUT + co) * D_ + d) * HW) + h * W_ + w0 + half * 4;
    *(float4*)dst = v;
  }
}

// ---------------- instance norm over (D,H,W) + exact GELU, in-place ----------------
__global__ __launch_bounds__(512) void k_norm_gelu(float* __restrict__ io) {
  const int M = D_ * HW;       // 18816
  const int M4 = M / 4;        // 4704
  float4* p = (float4*)(io + (size_t)blockIdx.x * M);
  float s = 0.f, s2 = 0.f;
  for (int i = threadIdx.x; i < M4; i += 512) {
    const float4 v = p[i];
    s += v.x + v.y + v.z + v.w;
    s2 = fmaf(v.x, v.x, fmaf(v.y, v.y, fmaf(v.z, v.z, fmaf(v.w, v.w, s2))));
  }
#pragma unroll
  for (int off = 32; off > 0; off >>= 1) {
    s += __shfl_down(s, off, 64);
    s2 += __shfl_down(s2, off, 64);
  }
  __shared__ float rs[8], rs2[8];
  __shared__ float smu, srstd;
  const int wid = threadIdx.x >> 6, lane = threadIdx.x & 63;
  if (lane == 0) { rs[wid] = s; rs2[wid] = s2; }
  __syncthreads();
  if (threadIdx.x == 0) {
    float ts = 0.f, t2 = 0.f;
#pragma unroll
    for (int i = 0; i < 8; ++i) { ts += rs[i]; t2 += rs2[i]; }
    const float mu = ts / (float)M;
    const float var = t2 / (float)M - mu * mu;
    smu = mu;
    srstd = rsqrtf(var + 1e-5f);
  }
  __syncthreads();
  const float mu = smu, rstd = srstd;
  for (int i = threadIdx.x; i < M4; i += 512) {
    float4 v = p[i];
    v.x = (v.x - mu) * rstd; v.y = (v.y - mu) * rstd;
    v.z = (v.z - mu) * rstd; v.w = (v.w - mu) * rstd;
    v.x = 0.5f * v.x * (1.f + erff(v.x * 0.70710678118654752f));
    v.y = 0.5f * v.y * (1.f + erff(v.y * 0.70710678118654752f));
    v.z = 0.5f * v.z * (1.f + erff(v.z * 0.70710678118654752f));
    v.w = 0.5f * v.w * (1.f + erff(v.w * 0.70710678118654752f));
    p[i] = v;
  }
}

extern "C" void kernel_launch(void* const* d_in, const int* in_sizes, int n_in,
                              void* d_out, int out_size, void* d_ws, size_t ws_size,
                              hipStream_t stream) {
  const float* x  = (const float*)d_in[0];
  const float* ow = (const float*)d_in[1];
  const float* ob = (const float*)d_in[2];
  const float* cw = (const float*)d_in[3];
  const float* cb = (const float*)d_in[4];
  float* outp = (float*)d_out;

  float* xcl  = (float*)d_ws;                       // 4,816,896 floats
  float* offb = xcl + (size_t)N_ * HW * C_;         // 2,709,504 floats
  float* wtt2 = offb + (size_t)N_ * OFFC * HW;      //    36,864 floats
  float* owt  = wtt2 + (size_t)COUT * CG * K2_;     //    82,944 floats (total ~30.6 MB)

  k_wt2<<<dim3(144), 256, 0, stream>>>(cw, wtt2);
  k_owt<<<dim3(324), 256, 0, stream>>>(ow, owt);
  k_transpose<<<dim3(H_, 4, N_), 256, 0, stream>>>(x, xcl);
  k_offset_conv<<<dim3(14, 9, N_), 256, 0, stream>>>(x, owt, ob, offb);
  k_deform<<<dim3(7, H_, N_), 256, 0, stream>>>(xcl, offb, wtt2, cb, outp);
  k_norm_gelu<<<dim3(B_ * COUT), 512, 0, stream>>>(outp);
}

// Round 3
// 230.100 us; speedup vs baseline: 3.3117x; 1.8577x over previous
//
#include <hip/hip_runtime.h>
#include <hip/hip_bf16.h>

typedef __attribute__((ext_vector_type(8))) short bf16x8;
typedef __attribute__((ext_vector_type(4))) float f32x4;

#define B_   2
#define C_   128
#define D_   6
#define H_   56
#define W_   56
#define N_   12      // B_*D_
#define HW   3136
#define CSTR (D_*HW) // 18816
#define COUT 128
#define OFFP 80      // padded offset-channel stride (72 used)

__device__ __forceinline__ float bf2f(ushort u) {
  return __uint_as_float(((unsigned int)u) << 16);
}
__device__ __forceinline__ ushort f2bf(float f) {  // RNE
  unsigned int x = __float_as_uint(f);
  x += 0x7FFFu + ((x >> 16) & 1u);
  return (ushort)(x >> 16);
}

// ---------------- x (b,c,d,h,w) f32 -> xcl[n][hw][c] bf16 ----------------
__global__ __launch_bounds__(256) void k_transpose(const float* __restrict__ x,
                                                   ushort* __restrict__ xcl) {
  __shared__ float tile[32][57];
  const int h = blockIdx.x, c0 = blockIdx.y * 32, n = blockIdx.z;
  const int b = n / D_, d = n % D_;
  const float* src = x + (((size_t)(b * C_ + c0) * D_ + d) * HW) + h * W_;
  for (int i = threadIdx.x; i < 32 * W_; i += 256) {
    const int c = i / W_, w = i - c * W_;
    tile[c][w] = src[(size_t)c * CSTR + w];
  }
  __syncthreads();
  ushort* dst = xcl + ((size_t)(n * HW + h * W_)) * C_ + c0;
  for (int i = threadIdx.x; i < 32 * W_; i += 256) {
    const int w = i >> 5, c = i & 31;
    dst[(size_t)w * C_ + c] = f2bf(tile[c][w]);
  }
}

// ---------------- conv_w (co,ci,ky,kx) f32 -> w2[co][k*32+ci] bf16 ----------------
__global__ void k_wdef(const float* __restrict__ cw, ushort* __restrict__ w2) {
  const int idx = blockIdx.x * 256 + threadIdx.x;  // < 128*288
  if (idx < COUT * 288) {
    const int co = idx / 288;
    const int kc = idx - co * 288;
    const int k = kc >> 5, ci = kc & 31;
    w2[idx] = f2bf(cw[((size_t)co * 32 + ci) * 9 + k]);
  }
}

// ---------------- offset_w (co,c,ky,kx) f32 -> wob[co][tap*128+c] bf16, 80 rows ----------------
__global__ void k_woff(const float* __restrict__ ow, ushort* __restrict__ wob) {
  const int idx = blockIdx.x * 256 + threadIdx.x;  // < 80*1152
  if (idx < OFFP * 1152) {
    const int co = idx / 1152;
    const int kc = idx - co * 1152;
    const int tap = kc >> 7, c = kc & 127;
    float v = 0.f;
    if (co < 72) v = ow[((size_t)co * C_ + c) * 9 + tap];
    wob[idx] = f2bf(v);
  }
}

// ---------------- offset conv via MFMA implicit GEMM ----------------
// grid (56, 12), block 256 (4 waves = 4 M-tiles of 16 px along one h-row)
__global__ __launch_bounds__(256) void k_offset_conv(const ushort* __restrict__ xcl,
    const ushort* __restrict__ wob, const float* __restrict__ ob,
    float* __restrict__ offb2) {
  __shared__ __align__(16) ushort xr[3 * 64 * 128];  // 49152 B, XOR-swizzled
  const int h = blockIdx.x, n = blockIdx.y;
  const int t = threadIdx.x;
  // stage rows h-1..h+1 (zero padded), slots ws=w+1; ws 0,57..63 zeroed
  for (int i = t; i < 2688; i += 256) {
    const int dy = i / 896;
    const int j = i - dy * 896;
    const int w = j >> 4;
    const int c0 = (j & 15) << 3;
    const int rr = h + dy - 1;
    const int ws = w + 1;
    const int db = (((dy * 64 + ws) * 128 + c0) * 2) ^ ((ws & 7) << 4);
    uint4 v = {0u, 0u, 0u, 0u};
    if ((unsigned)rr < (unsigned)H_)
      v = *(const uint4*)(xcl + ((size_t)(n * HW + rr * W_ + w)) * C_ + c0);
    *(uint4*)((char*)xr + db) = v;
  }
  for (int i = t; i < 384; i += 256) {
    const int dy = i / 128;
    const int r2 = i - dy * 128;
    const int sidx = r2 >> 4;
    const int c0 = (r2 & 15) << 3;
    const int ws = (sidx == 0) ? 0 : 56 + sidx;
    const int db = (((dy * 64 + ws) * 128 + c0) * 2) ^ ((ws & 7) << 4);
    const uint4 z = {0u, 0u, 0u, 0u};
    *(uint4*)((char*)xr + db) = z;
  }
  __syncthreads();
  const int l = t & 63, m = t >> 6;
  const int w0 = m * 16;
  const int lf = l & 15, q = l >> 4;
  f32x4 acc[5] = {};
#pragma unroll 2
  for (int ti = 0; ti < 36; ++ti) {
    const int tap = ti >> 2, kq = ti & 3;
    const int dy = tap / 3, kxr = tap - dy * 3;
    const int ws = min(w0 + lf + kxr, 63);
    const int ab = (((dy * 64 + ws) * 128 + kq * 32 + q * 8) * 2) ^ ((ws & 7) << 4);
    const bf16x8 a = *(const bf16x8*)((const char*)xr + ab);
    const int kc = tap * 128 + kq * 32 + q * 8;
#pragma unroll
    for (int nt = 0; nt < 5; ++nt) {
      const bf16x8 bb = *(const bf16x8*)(wob + (size_t)(nt * 16 + lf) * 1152 + kc);
      acc[nt] = __builtin_amdgcn_mfma_f32_16x16x32_bf16(a, bb, acc[nt], 0, 0, 0);
    }
  }
  float* orow = offb2 + (size_t)(n * HW + h * W_) * OFFP;
#pragma unroll
  for (int nt = 0; nt < 5; ++nt) {
    const int co = nt * 16 + lf;
    const float bias = (co < 72) ? ob[co] : 0.f;
#pragma unroll
    for (int r = 0; r < 4; ++r) {
      const int w = w0 + q * 4 + r;
      if (w < W_) orow[(size_t)w * OFFP + co] = acc[nt][r] + bias;
    }
  }
}

// ---------------- deformable conv: setup -> sample -> MFMA ----------------
// grid (196, 12), block 256. 16-px strip, 4 waves = 4 groups.
__global__ __launch_bounds__(256) void k_deform(const ushort* __restrict__ xcl,
    const float* __restrict__ offb2, const ushort* __restrict__ w2,
    const float* __restrict__ cb, float* __restrict__ out) {
  __shared__ __align__(16) ushort ss[16 * 1160];        // 37120 B, bf16 samples
  __shared__ __align__(16) unsigned char sm2[13824];    // swW+swO, later outs
  ushort* swW = (ushort*)sm2;           // 576*4 bf16 weights
  int* swO = (int*)(sm2 + 4608);        // 576*4 corner offsets
  float* outs = (float*)sm2;            // 128*20 f32 (aliased after barrier)

  const int hw0 = blockIdx.x * 16;
  const int n = blockIdx.y;
  const int t = threadIdx.x;

  // ---- setup: one bilinear item per (p,g,k)
  for (int i = t; i < 576; i += 256) {
    const int p = i / 36;
    const int r = i - p * 36;
    const int g = r / 9;
    const int k = r - g * 9;
    const int hw = hw0 + p;
    const int h = hw / 56;
    const int w = hw - h * 56;
    const float2 o2 = *(const float2*)(offb2 + (size_t)(n * HW + hw) * OFFP + g * 18 + 2 * k);
    const int ky = k / 3 - 1;
    const int kx = k - (k / 3) * 3 - 1;
    const float py = (float)(h + ky) + o2.x;
    const float px = (float)(w + kx) + o2.y;
    const float y0f = floorf(py), x0f = floorf(px);
    const float ly = py - y0f, lx = px - x0f;
    const int y0 = (int)y0f, x0 = (int)x0f;
    const int y1 = y0 + 1, x1 = x0 + 1;
    const int yc0 = min(max(y0, 0), H_ - 1), yc1 = min(max(y1, 0), H_ - 1);
    const int xc0 = min(max(x0, 0), W_ - 1), xc1 = min(max(x1, 0), W_ - 1);
    const float my0 = ((unsigned)y0 < (unsigned)H_) ? 1.f : 0.f;
    const float my1 = ((unsigned)y1 < (unsigned)H_) ? 1.f : 0.f;
    const float mx0 = ((unsigned)x0 < (unsigned)W_) ? 1.f : 0.f;
    const float mx1 = ((unsigned)x1 < (unsigned)W_) ? 1.f : 0.f;
    ushort4 wq;
    wq.x = f2bf((1.f - ly) * (1.f - lx) * my0 * mx0);
    wq.y = f2bf((1.f - ly) * lx * my0 * mx1);
    wq.z = f2bf(ly * (1.f - lx) * my1 * mx0);
    wq.w = f2bf(ly * lx * my1 * mx1);
    *(ushort4*)(swW + i * 4) = wq;
    const int gb = g * 32;
    int4 oq;
    oq.x = (yc0 * 56 + xc0) * 128 + gb;
    oq.y = (yc0 * 56 + xc1) * 128 + gb;
    oq.z = (yc1 * 56 + xc0) * 128 + gb;
    oq.w = (yc1 * 56 + xc1) * 128 + gb;
    *(int4*)(swO + i * 4) = oq;
  }
  __syncthreads();

  // ---- sampling: thread = (c, p); gathers only
  {
    const int c = t & 31;
    const int p0 = t >> 5;
    const ushort* xb = xcl + (size_t)n * HW * C_ + c;
#pragma unroll 1
    for (int hf = 0; hf < 2; ++hf) {
      const int p = p0 + 8 * hf;
#pragma unroll 1
      for (int g = 0; g < 4; ++g) {
        ushort* sd = ss + p * 1160 + g * 288 + c;
        const int ib = (p * 36 + g * 9) * 4;
#pragma unroll 3
        for (int k = 0; k < 9; ++k) {
          const ushort4 wq = *(const ushort4*)(swW + ib + k * 4);
          const int4 oq = *(const int4*)(swO + ib + k * 4);
          const float v00 = bf2f(xb[oq.x]);
          const float v01 = bf2f(xb[oq.y]);
          const float v10 = bf2f(xb[oq.z]);
          const float v11 = bf2f(xb[oq.w]);
          const float sres = fmaf(bf2f(wq.x), v00, fmaf(bf2f(wq.y), v01,
                             fmaf(bf2f(wq.z), v10, bf2f(wq.w) * v11)));
          sd[k * 32] = f2bf(sres);
        }
      }
    }
  }
  __syncthreads();

  // ---- MFMA: wave = group g; M=16 px, N=32 co (2 tiles), K=288
  const int l = t & 63;
  const int g = t >> 6;
  const int lf = l & 15, q = l >> 4;
  f32x4 acc0 = {}, acc1 = {};
  {
    const ushort* arow = ss + lf * 1160 + g * 288 + q * 8;
    const ushort* b0r = w2 + (size_t)(g * 32 + lf) * 288 + q * 8;
    const ushort* b1r = b0r + 16 * 288;
#pragma unroll
    for (int ts = 0; ts < 9; ++ts) {
      const bf16x8 a = *(const bf16x8*)(arow + ts * 32);
      const bf16x8 b0 = *(const bf16x8*)(b0r + ts * 32);
      const bf16x8 b1 = *(const bf16x8*)(b1r + ts * 32);
      acc0 = __builtin_amdgcn_mfma_f32_16x16x32_bf16(a, b0, acc0, 0, 0, 0);
      acc1 = __builtin_amdgcn_mfma_f32_16x16x32_bf16(a, b1, acc1, 0, 0, 0);
    }
  }
  // epilogue into padded LDS (aliases setup region; setup reads completed pre-barrier-2)
#pragma unroll
  for (int r = 0; r < 4; ++r) {
    outs[(g * 32 + lf) * 20 + q * 4 + r] = acc0[r] + cb[g * 32 + lf];
    outs[(g * 32 + 16 + lf) * 20 + q * 4 + r] = acc1[r] + cb[g * 32 + 16 + lf];
  }
  __syncthreads();
  {
    const int co = t & 127;
    const int hf = t >> 7;
    const float4 v0 = *(const float4*)(outs + co * 20 + hf * 8);
    const float4 v1 = *(const float4*)(outs + co * 20 + hf * 8 + 4);
    const int b = n / D_, d = n - b * D_;
    float* dst = out + ((size_t)(b * COUT + co) * D_ + d) * HW + hw0 + hf * 8;
    *(float4*)dst = v0;
    *(float4*)(dst + 4) = v1;
  }
}

// ---------------- instance norm over (D,H,W) + exact GELU, in-place ----------------
__global__ __launch_bounds__(512) void k_norm_gelu(float* __restrict__ io) {
  const int M = D_ * HW;       // 18816
  const int M4 = M / 4;        // 4704
  float4* p = (float4*)(io + (size_t)blockIdx.x * M);
  float s = 0.f, s2 = 0.f;
  for (int i = threadIdx.x; i < M4; i += 512) {
    const float4 v = p[i];
    s += v.x + v.y + v.z + v.w;
    s2 = fmaf(v.x, v.x, fmaf(v.y, v.y, fmaf(v.z, v.z, fmaf(v.w, v.w, s2))));
  }
#pragma unroll
  for (int off = 32; off > 0; off >>= 1) {
    s += __shfl_down(s, off, 64);
    s2 += __shfl_down(s2, off, 64);
  }
  __shared__ float rs[8], rs2[8];
  __shared__ float smu, srstd;
  const int wid = threadIdx.x >> 6, lane = threadIdx.x & 63;
  if (lane == 0) { rs[wid] = s; rs2[wid] = s2; }
  __syncthreads();
  if (threadIdx.x == 0) {
    float ts = 0.f, t2 = 0.f;
#pragma unroll
    for (int i = 0; i < 8; ++i) { ts += rs[i]; t2 += rs2[i]; }
    const float mu = ts / (float)M;
    const float var = t2 / (float)M - mu * mu;
    smu = mu;
    srstd = rsqrtf(var + 1e-5f);
  }
  __syncthreads();
  const float mu = smu, rstd = srstd;
  for (int i = threadIdx.x; i < M4; i += 512) {
    float4 v = p[i];
    v.x = (v.x - mu) * rstd; v.y = (v.y - mu) * rstd;
    v.z = (v.z - mu) * rstd; v.w = (v.w - mu) * rstd;
    v.x = 0.5f * v.x * (1.f + erff(v.x * 0.70710678118654752f));
    v.y = 0.5f * v.y * (1.f + erff(v.y * 0.70710678118654752f));
    v.z = 0.5f * v.z * (1.f + erff(v.z * 0.70710678118654752f));
    v.w = 0.5f * v.w * (1.f + erff(v.w * 0.70710678118654752f));
    p[i] = v;
  }
}

extern "C" void kernel_launch(void* const* d_in, const int* in_sizes, int n_in,
                              void* d_out, int out_size, void* d_ws, size_t ws_size,
                              hipStream_t stream) {
  const float* x  = (const float*)d_in[0];
  const float* ow = (const float*)d_in[1];
  const float* ob = (const float*)d_in[2];
  const float* cw = (const float*)d_in[3];
  const float* cb = (const float*)d_in[4];
  float* outp = (float*)d_out;

  char* wsb = (char*)d_ws;
  ushort* xcl   = (ushort*)wsb;                       // 12*3136*128*2 = 9,633,792 B
  float*  offb2 = (float*)(wsb + 9633792);            // 12*3136*80*4 = 12,042,240 B
  ushort* w2    = (ushort*)(wsb + 21676032);          // 128*288*2 = 73,728 B
  ushort* wob   = (ushort*)(wsb + 21749760);          // 80*1152*2 = 184,320 B

  k_wdef<<<dim3(144), 256, 0, stream>>>(cw, w2);
  k_woff<<<dim3(360), 256, 0, stream>>>(ow, wob);
  k_transpose<<<dim3(H_, 4, N_), 256, 0, stream>>>(x, xcl);
  k_offset_conv<<<dim3(H_, N_), 256, 0, stream>>>(xcl, wob, ob, offb2);
  k_deform<<<dim3(196, N_), 256, 0, stream>>>(xcl, offb2, w2, cb, outp);
  k_norm_gelu<<<dim3(B_ * COUT), 512, 0, stream>>>(outp);
}

// Round 4
// 169.521 us; speedup vs baseline: 4.4951x; 1.3574x over previous
//
#include <hip/hip_runtime.h>
#include <hip/hip_bf16.h>

typedef __attribute__((ext_vector_type(8))) short bf16x8;
typedef __attribute__((ext_vector_type(4))) float f32x4;

#define B_   2
#define C_   128
#define D_   6
#define H_   56
#define W_   56
#define N_   12      // B_*D_
#define HW   3136
#define CSTR (D_*HW) // 18816
#define COUT 128
#define OFFP 80      // padded offset-channel stride (72 used)

__device__ __forceinline__ float bf2f(ushort u) {
  return __uint_as_float(((unsigned int)u) << 16);
}
__device__ __forceinline__ ushort f2bf(float f) {  // RNE
  unsigned int x = __float_as_uint(f);
  x += 0x7FFFu + ((x >> 16) & 1u);
  return (ushort)(x >> 16);
}

// ---------------- x (b,c,d,h,w) f32 -> xcl[n][hw][c] bf16 ----------------
__global__ __launch_bounds__(256) void k_transpose(const float* __restrict__ x,
                                                   ushort* __restrict__ xcl) {
  __shared__ float tile[32][57];
  const int h = blockIdx.x, c0 = blockIdx.y * 32, n = blockIdx.z;
  const int b = n / D_, d = n % D_;
  const float* src = x + (((size_t)(b * C_ + c0) * D_ + d) * HW) + h * W_;
  for (int i = threadIdx.x; i < 32 * W_; i += 256) {
    const int c = i / W_, w = i - c * W_;
    tile[c][w] = src[(size_t)c * CSTR + w];
  }
  __syncthreads();
  ushort* dst = xcl + ((size_t)(n * HW + h * W_)) * C_ + c0;
  for (int i = threadIdx.x; i < 32 * W_; i += 256) {
    const int w = i >> 5, c = i & 31;
    dst[(size_t)w * C_ + c] = f2bf(tile[c][w]);
  }
}

// ---- conv_w (co,ci,ky,kx) f32 -> wd2[((g*36 + ts*4 + q)*32 + co_l)*8 + e] bf16 ----
// value = cw[((g*32+co_l)*32 + q*8 + e)*9 + ts]
__global__ void k_wdef2(const float* __restrict__ cw, ushort* __restrict__ wd2) {
  const int idx = blockIdx.x * 256 + threadIdx.x;  // < 36864
  if (idx < COUT * 288) {
    const int g = idx / 9216;
    const int r = idx - g * 9216;
    const int kb = r >> 8;           // 0..35
    const int co_l = (r >> 3) & 31;
    const int e = r & 7;
    const int ts = kb >> 2;
    const int q = kb & 3;
    wd2[idx] = f2bf(cw[((size_t)(g * 32 + co_l) * 32 + q * 8 + e) * 9 + ts]);
  }
}

// ---- offset_w (co,c,ky,kx) f32 -> wob2[((tap*16+kq*4+q)*80 + co)*8 + e] bf16 ----
// value = ow[(co*128 + kq*32+q*8+e)*9 + tap]  (co<72 else 0)
__global__ void k_woff2(const float* __restrict__ ow, ushort* __restrict__ wob2) {
  const int idx = blockIdx.x * 256 + threadIdx.x;  // < 92160
  if (idx < 144 * OFFP * 8) {
    const int e = idx & 7;
    const int co = (idx >> 3) % OFFP;
    const int kb = idx / (OFFP * 8);   // 0..143
    const int tap = kb >> 4;
    const int r16 = kb & 15;
    const int kq = r16 >> 2;
    const int q = r16 & 3;
    const int c = kq * 32 + q * 8 + e;
    float v = 0.f;
    if (co < 72) v = ow[((size_t)co * C_ + c) * 9 + tap];
    wob2[idx] = f2bf(v);
  }
}

// ---------------- offset conv via MFMA implicit GEMM ----------------
// grid (4, 56, 12), block 320 = 5 waves; wave nt owns N-tile of 16 co; M-tile 16 px
__global__ __launch_bounds__(320) void k_offset_conv(const ushort* __restrict__ xcl,
    const ushort* __restrict__ wob2, const float* __restrict__ ob,
    float* __restrict__ offb2) {
  __shared__ __align__(16) ushort xr[3 * 24 * 128];  // 18432 B, XOR-swizzled
  const int w0 = blockIdx.x * 16;
  const int h = blockIdx.y, n = blockIdx.z;
  const int t = threadIdx.x;
  // stage rows h-1..h+1, slots s=0..17 (w = w0-1+s), zero-padded
  for (int i = t; i < 864; i += 320) {
    const int c16 = i & 15;
    const int sdy = i >> 4;          // 0..53
    const int s = sdy % 18;
    const int dy = sdy / 18;
    const int w = w0 - 1 + s;
    const int rr = h + dy - 1;
    const int c0 = c16 * 8;
    const int db = (((dy * 24 + s) * 128 + c0) * 2) ^ ((s & 7) << 4);
    uint4 v = {0u, 0u, 0u, 0u};
    if ((unsigned)rr < (unsigned)H_ && (unsigned)w < (unsigned)W_)
      v = *(const uint4*)(xcl + ((size_t)(n * HW + rr * W_ + w)) * C_ + c0);
    *(uint4*)((char*)xr + db) = v;
  }
  __syncthreads();
  const int l = t & 63;
  const int nt = t >> 6;             // 0..4
  const int lf = l & 15, q = l >> 4; // q 0..3
  f32x4 acc = {};
#pragma unroll 3
  for (int tap = 0; tap < 9; ++tap) {
    const int dy = tap / 3, kxr = tap - dy * 3;
    const int s = lf + kxr;
#pragma unroll
    for (int kq = 0; kq < 4; ++kq) {
      const int ab = (((dy * 24 + s) * 128 + kq * 32 + q * 8) * 2) ^ ((s & 7) << 4);
      const bf16x8 a = *(const bf16x8*)((const char*)xr + ab);
      const bf16x8 bb = *(const bf16x8*)(wob2 +
          ((size_t)(tap * 16 + kq * 4 + q) * OFFP + nt * 16 + lf) * 8);
      acc = __builtin_amdgcn_mfma_f32_16x16x32_bf16(a, bb, acc, 0, 0, 0);
    }
  }
  const int co = nt * 16 + lf;
  const float bias = (co < 72) ? ob[co] : 0.f;
  float* orow = offb2 + ((size_t)n * HW + h * W_) * OFFP;
#pragma unroll
  for (int r = 0; r < 4; ++r) {
    const int w = w0 + q * 4 + r;
    if (w < W_) orow[(size_t)w * OFFP + co] = acc[r] + bias;
  }
}

// ---------------- deformable conv: setup -> sample -> MFMA ----------------
// grid (196, 12), block 256. 16-px strip, 4 waves = 4 groups in MFMA phase.
__global__ __launch_bounds__(256) void k_deform(const ushort* __restrict__ xcl,
    const float* __restrict__ offb2, const ushort* __restrict__ wd2,
    const float* __restrict__ cb, float* __restrict__ out) {
  __shared__ __align__(16) ushort ss[16 * 1160];        // 37120 B, bf16 samples
  __shared__ __align__(16) unsigned char sm2[14080];    // swW+swO, later outs
  ushort* swW = (ushort*)sm2;           // [p*144 + (g*9+k)*4], 4608 B
  int* swO = (int*)(sm2 + 4608);        // [p*148 + (g*9+k)*4], 9472 B
  float* outs = (float*)sm2;            // 128*20 f32 (aliased after barrier 2)

  const int hw0 = blockIdx.x * 16;
  const int n = blockIdx.y;
  const int t = threadIdx.x;

  // ---- setup: one bilinear item per (p,g,k)
  for (int i = t; i < 576; i += 256) {
    const int p = i / 36;
    const int r = i - p * 36;
    const int g = r / 9;
    const int k = r - g * 9;
    const int hw = hw0 + p;
    const int h = hw / 56;
    const int w = hw - h * 56;
    const float2 o2 = *(const float2*)(offb2 + (size_t)(n * HW + hw) * OFFP + g * 18 + 2 * k);
    const int ky = k / 3 - 1;
    const int kx = k - (k / 3) * 3 - 1;
    const float py = (float)(h + ky) + o2.x;
    const float px = (float)(w + kx) + o2.y;
    const float y0f = floorf(py), x0f = floorf(px);
    const float ly = py - y0f, lx = px - x0f;
    const int y0 = (int)y0f, x0 = (int)x0f;
    const int y1 = y0 + 1, x1 = x0 + 1;
    const int yc0 = min(max(y0, 0), H_ - 1), yc1 = min(max(y1, 0), H_ - 1);
    const int xc0 = min(max(x0, 0), W_ - 1), xc1 = min(max(x1, 0), W_ - 1);
    const float my0 = ((unsigned)y0 < (unsigned)H_) ? 1.f : 0.f;
    const float my1 = ((unsigned)y1 < (unsigned)H_) ? 1.f : 0.f;
    const float mx0 = ((unsigned)x0 < (unsigned)W_) ? 1.f : 0.f;
    const float mx1 = ((unsigned)x1 < (unsigned)W_) ? 1.f : 0.f;
    ushort4 wq;
    wq.x = f2bf((1.f - ly) * (1.f - lx) * my0 * mx0);
    wq.y = f2bf((1.f - ly) * lx * my0 * mx1);
    wq.z = f2bf(ly * (1.f - lx) * my1 * mx0);
    wq.w = f2bf(ly * lx * my1 * mx1);
    *(ushort4*)(swW + p * 144 + (g * 9 + k) * 4) = wq;
    const int gb = g * 32;
    int4 oq;
    oq.x = (yc0 * 56 + xc0) * 128 + gb;
    oq.y = (yc0 * 56 + xc1) * 128 + gb;
    oq.z = (yc1 * 56 + xc0) * 128 + gb;
    oq.w = (yc1 * 56 + xc1) * 128 + gb;
    *(int4*)(swO + p * 148 + (g * 9 + k) * 4) = oq;
  }
  __syncthreads();

  // ---- sampling: thread = (c4, p, gh); ushort4 gathers (4 channels/lane)
  {
    const int c4 = t & 7;
    const int p = (t >> 3) & 15;
    const int gh = t >> 7;           // 0..1
    const ushort* xb = xcl + (size_t)n * HW * C_ + c4 * 4;
#pragma unroll
    for (int gg = 0; gg < 2; ++gg) {
      const int g = gh * 2 + gg;
      ushort* sd = ss + p * 1160 + g * 288 + c4 * 4;
      const int wb = p * 144 + g * 36;
      const int obi = p * 148 + g * 36;
#pragma unroll 3
      for (int k = 0; k < 9; ++k) {
        const ushort4 wq = *(const ushort4*)(swW + wb + k * 4);
        const int4 oq = *(const int4*)(swO + obi + k * 4);
        const ushort4 a0 = *(const ushort4*)(xb + oq.x);
        const ushort4 a1 = *(const ushort4*)(xb + oq.y);
        const ushort4 a2 = *(const ushort4*)(xb + oq.z);
        const ushort4 a3 = *(const ushort4*)(xb + oq.w);
        const float w00 = bf2f(wq.x), w01 = bf2f(wq.y);
        const float w10 = bf2f(wq.z), w11 = bf2f(wq.w);
        ushort4 rr;
        rr.x = f2bf(fmaf(w00, bf2f(a0.x), fmaf(w01, bf2f(a1.x), fmaf(w10, bf2f(a2.x), w11 * bf2f(a3.x)))));
        rr.y = f2bf(fmaf(w00, bf2f(a0.y), fmaf(w01, bf2f(a1.y), fmaf(w10, bf2f(a2.y), w11 * bf2f(a3.y)))));
        rr.z = f2bf(fmaf(w00, bf2f(a0.z), fmaf(w01, bf2f(a1.z), fmaf(w10, bf2f(a2.z), w11 * bf2f(a3.z)))));
        rr.w = f2bf(fmaf(w00, bf2f(a0.w), fmaf(w01, bf2f(a1.w), fmaf(w10, bf2f(a2.w), w11 * bf2f(a3.w)))));
        *(ushort4*)(sd + k * 32) = rr;
      }
    }
  }
  __syncthreads();

  // ---- MFMA: wave = group g; M=16 px, N=32 co (2 tiles), K=288
  const int l = t & 63;
  const int g = t >> 6;
  const int lf = l & 15, q = l >> 4;
  f32x4 acc0 = {}, acc1 = {};
  {
    const ushort* arow = ss + lf * 1160 + g * 288 + q * 8;
    const ushort* bb = wd2 + (size_t)g * 36 * 32 * 8 + (size_t)q * 32 * 8 + lf * 8;
#pragma unroll
    for (int ts = 0; ts < 9; ++ts) {
      const bf16x8 a = *(const bf16x8*)(arow + ts * 32);
      const bf16x8 b0 = *(const bf16x8*)(bb + ts * 4 * 32 * 8);
      const bf16x8 b1 = *(const bf16x8*)(bb + ts * 4 * 32 * 8 + 16 * 8);
      acc0 = __builtin_amdgcn_mfma_f32_16x16x32_bf16(a, b0, acc0, 0, 0, 0);
      acc1 = __builtin_amdgcn_mfma_f32_16x16x32_bf16(a, b1, acc1, 0, 0, 0);
    }
  }
  // epilogue into padded LDS (aliases setup region; dead after barrier 2)
#pragma unroll
  for (int r = 0; r < 4; ++r) {
    outs[(g * 32 + lf) * 20 + q * 4 + r] = acc0[r] + cb[g * 32 + lf];
    outs[(g * 32 + 16 + lf) * 20 + q * 4 + r] = acc1[r] + cb[g * 32 + 16 + lf];
  }
  __syncthreads();
  {
    const int co = t & 127;
    const int hf = t >> 7;
    const float4 v0 = *(const float4*)(outs + co * 20 + hf * 8);
    const float4 v1 = *(const float4*)(outs + co * 20 + hf * 8 + 4);
    const int b = n / D_, d = n - b * D_;
    float* dst = out + ((size_t)(b * COUT + co) * D_ + d) * HW + hw0 + hf * 8;
    *(float4*)dst = v0;
    *(float4*)(dst + 4) = v1;
  }
}

// ---------------- instance norm over (D,H,W) + exact GELU, in-place ----------------
__global__ __launch_bounds__(512) void k_norm_gelu(float* __restrict__ io) {
  const int M = D_ * HW;       // 18816
  const int M4 = M / 4;        // 4704
  float4* p = (float4*)(io + (size_t)blockIdx.x * M);
  float s = 0.f, s2 = 0.f;
  for (int i = threadIdx.x; i < M4; i += 512) {
    const float4 v = p[i];
    s += v.x + v.y + v.z + v.w;
    s2 = fmaf(v.x, v.x, fmaf(v.y, v.y, fmaf(v.z, v.z, fmaf(v.w, v.w, s2))));
  }
#pragma unroll
  for (int off = 32; off > 0; off >>= 1) {
    s += __shfl_down(s, off, 64);
    s2 += __shfl_down(s2, off, 64);
  }
  __shared__ float rs[8], rs2[8];
  __shared__ float smu, srstd;
  const int wid = threadIdx.x >> 6, lane = threadIdx.x & 63;
  if (lane == 0) { rs[wid] = s; rs2[wid] = s2; }
  __syncthreads();
  if (threadIdx.x == 0) {
    float ts = 0.f, t2 = 0.f;
#pragma unroll
    for (int i = 0; i < 8; ++i) { ts += rs[i]; t2 += rs2[i]; }
    const float mu = ts / (float)M;
    const float var = t2 / (float)M - mu * mu;
    smu = mu;
    srstd = rsqrtf(var + 1e-5f);
  }
  __syncthreads();
  const float mu = smu, rstd = srstd;
  for (int i = threadIdx.x; i < M4; i += 512) {
    float4 v = p[i];
    v.x = (v.x - mu) * rstd; v.y = (v.y - mu) * rstd;
    v.z = (v.z - mu) * rstd; v.w = (v.w - mu) * rstd;
    v.x = 0.5f * v.x * (1.f + erff(v.x * 0.70710678118654752f));
    v.y = 0.5f * v.y * (1.f + erff(v.y * 0.70710678118654752f));
    v.z = 0.5f * v.z * (1.f + erff(v.z * 0.70710678118654752f));
    v.w = 0.5f * v.w * (1.f + erff(v.w * 0.70710678118654752f));
    p[i] = v;
  }
}

extern "C" void kernel_launch(void* const* d_in, const int* in_sizes, int n_in,
                              void* d_out, int out_size, void* d_ws, size_t ws_size,
                              hipStream_t stream) {
  const float* x  = (const float*)d_in[0];
  const float* ow = (const float*)d_in[1];
  const float* ob = (const float*)d_in[2];
  const float* cw = (const float*)d_in[3];
  const float* cb = (const float*)d_in[4];
  float* outp = (float*)d_out;

  char* wsb = (char*)d_ws;
  ushort* xcl   = (ushort*)wsb;                       // 9,633,792 B
  float*  offb2 = (float*)(wsb + 9633792);            // 12,042,240 B
  ushort* wd2   = (ushort*)(wsb + 21676032);          // 73,728 B
  ushort* wob2  = (ushort*)(wsb + 21749760);          // 184,320 B

  k_wdef2<<<dim3(144), 256, 0, stream>>>(cw, wd2);
  k_woff2<<<dim3(360), 256, 0, stream>>>(ow, wob2);
  k_transpose<<<dim3(H_, 4, N_), 256, 0, stream>>>(x, xcl);
  k_offset_conv<<<dim3(4, H_, N_), 320, 0, stream>>>(xcl, wob2, ob, offb2);
  k_deform<<<dim3(196, N_), 256, 0, stream>>>(xcl, offb2, wd2, cb, outp);
  k_norm_gelu<<<dim3(B_ * COUT), 512, 0, stream>>>(outp);
}